// Round 5
// baseline (198.759 us; speedup 1.0000x reference)
//
#include <hip/hip_runtime.h>

// Layer sizes: 500 -> 400 -> 300 -> 200 -> 100
// ws layout (u32 words): MA@0 (500*16), MB@8000 (400*16), V@14400, SH@14912,
// SC@15424, IDX@15936, HSEL@16448, RSUM@16960, SU@17472, SU2@17984, BAR@18496(32)

#define MS 16
#define NB 125

struct P4 { const float* p[4]; };

__device__ __forceinline__ float bitselF(unsigned m, int k, float v) {
    int s = ((int)(m << (31 - k))) >> 31;
    return __int_as_float(s & __float_as_int(v));
}
__device__ __forceinline__ float fbfly(float v) {
#pragma unroll
    for (int o = 32; o; o >>= 1) v += __shfl_xor(v, o);
    return v;
}
__device__ __forceinline__ int ibfly(int v) {
#pragma unroll
    for (int o = 32; o; o >>= 1) v += __shfl_xor(v, o);
    return v;
}

// Device-scope grid barrier: monotonic counter per phase, reset by k_dot each
// launch. 125 blocks always co-resident (256 thr = 4 waves/blk) -> no deadlock.
__device__ __forceinline__ void gbar(unsigned* c, int nb) {
    __syncthreads();
    if (threadIdx.x == 0) {
        __threadfence();
        __hip_atomic_fetch_add(c, 1u, __ATOMIC_ACQ_REL, __HIP_MEMORY_SCOPE_AGENT);
        while (__hip_atomic_load(c, __ATOMIC_ACQUIRE, __HIP_MEMORY_SCOPE_AGENT) <
               (unsigned)nb)
            __builtin_amdgcn_s_sleep(1);
        __threadfence();
    }
    __syncthreads();
}

// V[row] = dot(h[row,:], Wt); MA[row] = bitmask of g row; resets BAR.
__global__ __launch_bounds__(1024) void k_dot(const float* __restrict__ h,
        const float* __restrict__ Wt, const float* __restrict__ g,
        float* __restrict__ V, unsigned* __restrict__ MA,
        unsigned* __restrict__ BAR) {
    int row = blockIdx.x, t = threadIdx.x;
    if (row == 0 && t < 32) BAR[t] = 0u;
    const float4* h4 = (const float4*)(h + (size_t)row * 32768);
    const float4* w4 = (const float4*)Wt;
    float acc = 0.f;
#pragma unroll
    for (int j = 0; j < 8; ++j) {
        float4 a = h4[t + 1024 * j], b = w4[t + 1024 * j];
        acc = fmaf(a.x, b.x, fmaf(a.y, b.y, fmaf(a.z, b.z, fmaf(a.w, b.w, acc))));
    }
    acc = fbfly(acc);
    __shared__ float red[16];
    if ((t & 63) == 0) red[t >> 6] = acc;
    __syncthreads();
    if (t == 0) {
        float s = 0.f;
        for (int i = 0; i < 16; ++i) s += red[i];
        V[row] = s;
    }
    if (t < 512) {
        float gv = (t < 500) ? g[row * 500 + t] : 0.f;
        unsigned long long bal = __ballot(gv != 0.f);
        if ((t & 63) == 0) {
            int w = t >> 6;
            MA[row * MS + 2 * w] = (unsigned)bal;
            MA[row * MS + 2 * w + 1] = (unsigned)(bal >> 32);
        }
    }
}

// Everything else: persistent kernel, 125 blocks x 256 threads, 1 wave per row.
__global__ __launch_bounds__(256) void k_main(const float* __restrict__ V,
        unsigned* __restrict__ MA, unsigned* __restrict__ MB,
        float* __restrict__ SH, float* __restrict__ SC, int* __restrict__ IDX,
        float* __restrict__ HSEL, float* __restrict__ RSUM,
        float* __restrict__ SU, float* __restrict__ SU2,
        unsigned* __restrict__ BAR, const float* __restrict__ b_top,
        P4 Wp, P4 bp, P4 Wd, P4 bd, float* __restrict__ out) {
    __shared__ float sv[512];
    __shared__ float stot;
    int t = threadIdx.x, bid = blockIdx.x;
    int wid = t >> 6, lane = t & 63;
    int r4 = bid * 4 + wid;
    int barp = 0;

    // ---- P0: SH = relu(MA . V + b_top); out[0:500] ----
    sv[t] = (t < 500) ? V[t] : 0.f;
    sv[t + 256] = (t + 256 < 500) ? V[t + 256] : 0.f;
    __syncthreads();
    if (r4 < 500) {
        float acc = 0.f;
#pragma unroll
        for (int j = 0; j < 8; ++j) {
            unsigned m = MA[r4 * MS + 2 * j + (lane >> 5)];
            acc += bitselF(m, lane & 31, sv[64 * j + lane]);
        }
        acc = fbfly(acc);
        if (lane == 0) {
            float hv = fmaxf(acc + b_top[0], 0.f);
            SH[r4] = hv;
            out[r4] = hv;
        }
    }
    gbar(BAR + barp++, NB);

    // ---- P1: SC = sigmoid(relu((MA . SH) * Wp0 + bp0)) ----
    __syncthreads();
    sv[t] = (t < 500) ? SH[t] : 0.f;
    sv[t + 256] = (t + 256 < 500) ? SH[t + 256] : 0.f;
    __syncthreads();
    if (r4 < 500) {
        float acc = 0.f;
#pragma unroll
        for (int j = 0; j < 8; ++j) {
            unsigned m = MA[r4 * MS + 2 * j + (lane >> 5)];
            acc += bitselF(m, lane & 31, sv[64 * j + lane]);
        }
        acc = fbfly(acc);
        if (lane == 0) {
            float x = fmaxf(acc * Wp.p[0][0] + bp.p[0][0], 0.f);
            SC[r4] = 1.f / (1.f + expf(-x));
        }
    }
    gbar(BAR + barp++, NB);

    // ---- P2: stable-rank top-400 ----
    __syncthreads();
    sv[t] = (t < 500) ? SC[t] : 0.f;
    sv[t + 256] = (t + 256 < 500) ? SC[t + 256] : 0.f;
    __syncthreads();
    if (r4 < 500) {
        float my = sv[r4];
        int cnt = 0;
#pragma unroll
        for (int jj = 0; jj < 8; ++jj) {
            int j = jj * 64 + lane;
            float sj = sv[j];
            cnt += (sj > my) || (sj == my && j < r4);
        }
        cnt = ibfly(cnt);
        if (lane == 0 && cnt < 400) {
            IDX[cnt] = r4;
            HSEL[cnt] = SH[r4] * my;
        }
    }
    gbar(BAR + barp++, NB);

    // ---- 4 pooling layers ----
    const int ns[4] = {500, 400, 300, 200};
    const int kks[4] = {400, 300, 200, 100};
    const int offs[4] = {500, 900, 1200, 1400};
#pragma unroll
    for (int l = 0; l < 4; ++l) {
        const int n = ns[l], kk = kks[l];
        const int knext = (l < 3) ? kks[l + 1] : 0;
        unsigned* Mc = (l & 1) ? MB : MA;
        unsigned* Mn = (l & 1) ? MA : MB;
        const int Wc = (n + 31) >> 5;
        int w = lane & 15, part = lane >> 4;

        // -- twohop: un2 row of selected node, compact to new index space --
        if (r4 < kk) {
            int i = IDX[r4];
            unsigned srw = (w < Wc) ? Mc[i * MS + w] : 0u;
            unsigned acc = 0;
#pragma unroll
            for (int qi = 0; qi < 4; ++qi) {
                int q = part + qi * 4;
                if (q * 32 < n) {
                    unsigned sw = (unsigned)__shfl((int)srw, (lane & 48) | q);
                    const unsigned* col = Mc + (q * 32) * MS + w;
#pragma unroll
                    for (int b = 0; b < 32; ++b) {
                        int s = ((int)(sw << (31 - b))) >> 31;
                        acc |= col[b * MS] & (unsigned)s;
                    }
                }
            }
            acc |= (unsigned)__shfl_xor((int)acc, 16);
            acc |= (unsigned)__shfl_xor((int)acc, 32);
            // all lanes now hold un2 word (lane&15)
            unsigned long long cnt = 0;
            for (int c0 = 0; c0 < kk; c0 += 64) {
                int c = c0 + lane;
                int ok = 0;
                if (c < kk) {
                    int j = IDX[c];
                    unsigned uw = (unsigned)__shfl((int)acc, (lane & 48) | (j >> 5));
                    ok = (uw >> (j & 31)) & 1;
                }
                unsigned long long bits = __ballot(ok);
                if (lane == 0) {
                    Mn[r4 * MS + (c0 >> 5)] = (unsigned)bits;
                    Mn[r4 * MS + (c0 >> 5) + 1] = (unsigned)(bits >> 32);
                }
                cnt += __popcll(bits);
            }
            if (lane == 0) {
                float cf = (float)cnt;
                RSUM[r4] = cf;
                SU[r4] = HSEL[r4] * Wd.p[l][r4] / cf;
            }
        }
        gbar(BAR + barp++, NB);

        // -- midA: hv = relu(total(SU) - complement + bd); out_seg; SU2 --
        __syncthreads();
        sv[t] = (t < kk) ? SU[t] : 0.f;
        sv[t + 256] = (t + 256 < kk) ? SU[t + 256] : 0.f;
        __syncthreads();
        if (wid == 0) {
            float p = 0.f;
#pragma unroll
            for (int j = 0; j < 8; ++j) p += sv[lane * 8 + j];
            p = fbfly(p);
            if (lane == 0) stot = p;
        }
        __syncthreads();
        if (r4 < kk) {
            int base = w * 32;
            unsigned wm = (kk - base >= 32) ? 0xffffffffu
                         : ((kk > base) ? ((1u << (kk - base)) - 1u) : 0u);
            unsigned inv = ~Mn[r4 * MS + w] & wm;
            unsigned sub = (inv >> (part * 8)) & 0xffu;
            float corr = 0.f;
            while (sub) {
                int b = __ffs(sub) - 1;
                sub &= sub - 1;
                corr += sv[base + part * 8 + b];
            }
            corr = fbfly(corr);
            float hv = fmaxf((stot - corr) + bd.p[l][0], 0.f);
            if (lane == 0) {
                out[offs[l] + r4] = hv;
                SH[r4] = hv;
                SU2[r4] = hv / RSUM[r4];
            }
        }
        if (knext == 0) break;
        gbar(BAR + barp++, NB);

        // -- midB: next-layer scores --
        __syncthreads();
        sv[t] = (t < kk) ? SU2[t] : 0.f;
        sv[t + 256] = (t + 256 < kk) ? SU2[t + 256] : 0.f;
        __syncthreads();
        if (wid == 0) {
            float p = 0.f;
#pragma unroll
            for (int j = 0; j < 8; ++j) p += sv[lane * 8 + j];
            p = fbfly(p);
            if (lane == 0) stot = p;
        }
        __syncthreads();
        if (r4 < kk) {
            int base = w * 32;
            unsigned wm = (kk - base >= 32) ? 0xffffffffu
                         : ((kk > base) ? ((1u << (kk - base)) - 1u) : 0u);
            unsigned inv = ~Mn[r4 * MS + w] & wm;
            unsigned sub = (inv >> (part * 8)) & 0xffu;
            float corr = 0.f;
            while (sub) {
                int b = __ffs(sub) - 1;
                sub &= sub - 1;
                corr += sv[base + part * 8 + b];
            }
            corr = fbfly(corr);
            float x = fmaxf((stot - corr) * Wp.p[l + 1][0] + bp.p[l + 1][0], 0.f);
            if (lane == 0) SC[r4] = 1.f / (1.f + expf(-x));
        }
        gbar(BAR + barp++, NB);

        // -- rank: top-knext of kk scores --
        __syncthreads();
        sv[t] = (t < kk) ? SC[t] : 0.f;
        sv[t + 256] = (t + 256 < kk) ? SC[t + 256] : 0.f;
        __syncthreads();
        if (r4 < kk) {
            float my = sv[r4];
            int cnt = 0;
#pragma unroll
            for (int jj = 0; jj < 8; ++jj) {
                int j = jj * 64 + lane;
                float sj = sv[j];
                cnt += (sj > my) || (sj == my && j < r4);
            }
            cnt = ibfly(cnt);
            if (lane == 0 && cnt < knext) {
                IDX[cnt] = r4;
                HSEL[cnt] = SH[r4] * my;
            }
        }
        gbar(BAR + barp++, NB);
    }
}

extern "C" void kernel_launch(void* const* d_in, const int* in_sizes, int n_in,
                              void* d_out, int out_size, void* d_ws, size_t ws_size,
                              hipStream_t stream) {
    const float* g = (const float*)d_in[0];
    const float* h = (const float*)d_in[1];
    const float* W_top = (const float*)d_in[2];
    const float* b_top = (const float*)d_in[3];
    P4 Wp, bp, Wd, bd;
    for (int i = 0; i < 4; ++i) {
        Wp.p[i] = (const float*)d_in[4 + 4 * i];
        bp.p[i] = (const float*)d_in[5 + 4 * i];
        Wd.p[i] = (const float*)d_in[6 + 4 * i];
        bd.p[i] = (const float*)d_in[7 + 4 * i];
    }
    float* out = (float*)d_out;

    unsigned* wsu = (unsigned*)d_ws;
    unsigned* MA = wsu + 0;
    unsigned* MB = wsu + 8000;
    float* V = (float*)(wsu + 14400);
    float* SH = (float*)(wsu + 14912);
    float* SC = (float*)(wsu + 15424);
    int* IDX = (int*)(wsu + 15936);
    float* HSEL = (float*)(wsu + 16448);
    float* RSUM = (float*)(wsu + 16960);
    float* SU = (float*)(wsu + 17472);
    float* SU2 = (float*)(wsu + 17984);
    unsigned* BAR = wsu + 18496;

    k_dot<<<500, 1024, 0, stream>>>(h, W_top, g, V, MA, BAR);
    k_main<<<NB, 256, 0, stream>>>(V, MA, MB, SH, SC, IDX, HSEL, RSUM, SU, SU2,
                                   BAR, b_top, Wp, bp, Wd, bd, out);
}

// Round 6
// 117.350 us; speedup vs baseline: 1.6937x; 1.6937x over previous
//
#include <hip/hip_runtime.h>

// Everything lives in ORIGINAL 500-node index space. Active set = SELM bitmask;
// ordering = POS (orig -> compact rank) + IDXL (compact -> orig).
// Graphs for layers >=1 are stored as per-row COMPLEMENT masks CPg (~2-3 bits
// set, since 2-hop graphs are ~99.5% dense).
// ws layout (u32 words): V@0, POS@512, HSELo@1024, RSUMo@1536, SUo@2048,
// SELM@2560(32), IDXL@2592, CPg@3104(8000), MA@11104(8000)

#define MS 16

__device__ __forceinline__ float fbfly(float v) {
#pragma unroll
    for (int o = 32; o; o >>= 1) v += __shfl_xor(v, o);
    return v;
}

// sparse masked dot over words [w0,w1): walk set bits only (~3/word for g)
__device__ __forceinline__ float pwalk(const unsigned* __restrict__ row, int w0,
                                       int w1, const float* __restrict__ val) {
    float a = 0.f;
    for (int w = w0; w < w1; ++w) {
        unsigned m = row[w];
        while (m) {
            int b = __ffs(m) - 1;
            m &= m - 1;
            a += val[(w << 5) + b];
        }
    }
    return a;
}

// V[row] = dot(h[row,:], Wt); MA[row] = bitmask of g row.
__global__ __launch_bounds__(1024) void k_dot(const float* __restrict__ h,
        const float* __restrict__ Wt, const float* __restrict__ g,
        float* __restrict__ V, unsigned* __restrict__ MA) {
    int row = blockIdx.x, t = threadIdx.x;
    const float4* h4 = (const float4*)(h + (size_t)row * 32768);
    const float4* w4 = (const float4*)Wt;
    float acc = 0.f;
#pragma unroll
    for (int j = 0; j < 8; ++j) {
        float4 a = h4[t + 1024 * j], b = w4[t + 1024 * j];
        acc = fmaf(a.x, b.x, fmaf(a.y, b.y, fmaf(a.z, b.z, fmaf(a.w, b.w, acc))));
    }
    acc = fbfly(acc);
    __shared__ float red[16];
    if ((t & 63) == 0) red[t >> 6] = acc;
    __syncthreads();
    if (t == 0) {
        float s = 0.f;
        for (int i = 0; i < 16; ++i) s += red[i];
        V[row] = s;
    }
    if (t < 512) {
        float gv = (t < 500) ? g[row * 500 + t] : 0.f;
        unsigned long long bal = __ballot(gv != 0.f);
        if ((t & 63) == 0) {
            int w = t >> 6;
            MA[row * MS + 2 * w] = (unsigned)bal;
            MA[row * MS + 2 * w + 1] = (unsigned)(bal >> 32);
        }
    }
}

// P0 (h_top) + P1 (scores) + top-400 rank. 1 block x 1024, masks in LDS.
__global__ __launch_bounds__(1024) void k_top(const unsigned* __restrict__ MA,
        const float* __restrict__ V, const float* __restrict__ b_top,
        const float* __restrict__ Wp0, const float* __restrict__ bp0,
        float* __restrict__ out, int* __restrict__ POSg, int* __restrict__ IDXL,
        float* __restrict__ HSELo, unsigned* __restrict__ SELM) {
    __shared__ unsigned sMA[8000];
    __shared__ float sv[512], sh[512], sco[512];
    __shared__ unsigned sSELM[16];
    int t = threadIdx.x;
    for (int i = t; i < 8000; i += 1024) sMA[i] = MA[i];
    if (t < 512) {
        sv[t] = (t < 500) ? V[t] : 0.f;
        sh[t] = 0.f;
        sco[t] = 0.f;
    }
    if (t < 16) sSELM[t] = 0u;
    __syncthreads();
    int row = t >> 1, hf = t & 1, w0 = hf * 8, w1 = w0 + 8;
    if (row < 500) {
        float acc = pwalk(sMA + row * MS, w0, w1, sv);
        acc += __shfl_xor(acc, 1);
        if (!hf) {
            float hv = fmaxf(acc + b_top[0], 0.f);
            sh[row] = hv;
            out[row] = hv;
        }
    }
    __syncthreads();
    if (row < 500) {
        float acc = pwalk(sMA + row * MS, w0, w1, sh);
        acc += __shfl_xor(acc, 1);
        if (!hf) {
            float x = fmaxf(acc * Wp0[0] + bp0[0], 0.f);
            sco[row] = 1.f / (1.f + expf(-x));
        }
    }
    __syncthreads();
    if (t < 500) {
        float my = sco[t];
        int cnt = 0;
        for (int q = 0; q < 512; q += 4) {
            float4 v = *(const float4*)(sco + q);
            cnt += (v.x > my) || (v.x == my && (q + 0) < t);
            cnt += (v.y > my) || (v.y == my && (q + 1) < t);
            cnt += (v.z > my) || (v.z == my && (q + 2) < t);
            cnt += (v.w > my) || (v.w == my && (q + 3) < t);
        }
        if (cnt < 400) {
            POSg[t] = cnt;
            IDXL[cnt] = t;
            HSELo[t] = sh[t] * my;
            atomicOr(&sSELM[t >> 5], 1u << (t & 31));
        } else {
            POSg[t] = -1;
        }
    }
    __syncthreads();
    if (t < 16) SELM[t] = sSELM[t];
}

// Layer-0 twohop on the SPARSE g: dense column scan, 100 blocks, wave/row.
// Emits complement rows CPg (orig space), RSUMo, SUo.
__global__ __launch_bounds__(256) void k_twohop0(const unsigned* __restrict__ MA,
        const int* __restrict__ IDXL, const unsigned* __restrict__ SELM,
        const float* __restrict__ HSELo, const float* __restrict__ Wd0,
        unsigned* __restrict__ CPg, float* __restrict__ RSUMo,
        float* __restrict__ SUo) {
    int wid = threadIdx.x >> 6, lane = threadIdx.x & 63;
    int r4 = blockIdx.x * 4 + wid;  // compact row
    int i = IDXL[r4];               // orig node
    __shared__ unsigned sSEL[16];
    __shared__ unsigned srow[4][16];
    __shared__ unsigned un2[4][16];
    if (threadIdx.x < 16) sSEL[threadIdx.x] = SELM[threadIdx.x];
    if (lane < 16) {
        srow[wid][lane] = MA[i * MS + lane];
        un2[wid][lane] = 0u;
    }
    __syncthreads();
    int part = lane >> 4, w = lane & 15;
    unsigned acc = 0;
    for (int k = part; k < 500; k += 4) {
        unsigned sel = (srow[wid][k >> 5] >> (k & 31)) & 1u;
        acc |= MA[k * MS + w] & (0u - sel);
    }
    atomicOr(&un2[wid][w], acc);
    __syncthreads();
    if (lane < 16) {
        unsigned Pw = sSEL[lane] & ~un2[wid][lane];
        CPg[i * MS + lane] = Pw;
        int pc = __popc(Pw);
        pc += __shfl_xor(pc, 1);
        pc += __shfl_xor(pc, 2);
        pc += __shfl_xor(pc, 4);
        pc += __shfl_xor(pc, 8);
        if (lane == 0) {
            float rs = (float)(400 - pc);
            RSUMo[i] = rs;
            SUo[i] = HSELo[i] * Wd0[r4] / rs;
        }
    }
}

// One kernel per layer: midA (down-GCN via total-complement) -> out,
// midB (scores), rank (compact, index tie-break), twohop (complement
// intersect with early exit). 1 block x 1024 threads.
__global__ __launch_bounds__(1024) void k_layer(unsigned* __restrict__ CPg,
        unsigned* __restrict__ SELM, int* __restrict__ POSg,
        int* __restrict__ IDXL, float* __restrict__ RSUMo,
        float* __restrict__ SUo, const float* __restrict__ bd,
        const float* __restrict__ Wp, const float* __restrict__ bp,
        const float* __restrict__ Wdn, float* __restrict__ out,
        int kk, int knext, int out_off) {
    __shared__ unsigned sCP[8000];
    __shared__ unsigned sSEL[16], sSELn[16];
    __shared__ float sSU[512], sSU2[512], sRS[512], sH[512], sKc[512], sHS[512];
    __shared__ int sPOS[512], sNP[512], sIDX[512], sIDXn[512];
    __shared__ float sTot[2];
    int t = threadIdx.x;
    for (int i = t; i < 8000; i += 1024) sCP[i] = CPg[i];
    if (t < 16) { sSEL[t] = SELM[t]; sSELn[t] = 0u; }
    if (t < 512) {
        int act = (t < 500) ? (int)((SELM[t >> 5] >> (t & 31)) & 1u) : 0;
        sSU[t] = act ? SUo[t] : 0.f;
        sRS[t] = (t < 500) ? RSUMo[t] : 1.f;
        sPOS[t] = (t < 500) ? POSg[t] : -1;
        sIDX[t] = (t < kk) ? IDXL[t] : 0;
        sKc[t] = 0.f;
        sSU2[t] = 0.f;
        sH[t] = 0.f;
    }
    __syncthreads();
    // total(su) fixed tree
    if (t < 64) {
        float p = 0.f;
#pragma unroll
        for (int j = 0; j < 8; ++j) p += sSU[t * 8 + j];
        p = fbfly(p);
        if (t == 0) sTot[0] = p;
    }
    __syncthreads();
    bool act = (t < 500) && ((sSEL[t >> 5] >> (t & 31)) & 1u);
    if (act) {
        float corr = pwalk(sCP + t * MS, 0, 16, sSU);
        float hv = fmaxf((sTot[0] - corr) + bd[0], 0.f);
        out[out_off + sPOS[t]] = hv;
        sH[t] = hv;
        sSU2[t] = hv / sRS[t];
    }
    __syncthreads();
    if (knext == 0) return;
    if (t < 64) {
        float p = 0.f;
#pragma unroll
        for (int j = 0; j < 8; ++j) p += sSU2[t * 8 + j];
        p = fbfly(p);
        if (t == 0) sTot[1] = p;
    }
    __syncthreads();
    if (act) {
        float c2 = pwalk(sCP + t * MS, 0, 16, sSU2);
        float x = fmaxf((sTot[1] - c2) * Wp[0] + bp[0], 0.f);
        sKc[sPOS[t]] = 1.f / (1.f + expf(-x));  // compact-ordered score
    }
    __syncthreads();
    // rank over compact array, tie-break by compact index
    if (t < kk) {
        float my = sKc[t];
        int cnt = 0;
        for (int q = 0; q < 512; q += 4) {
            float4 v = *(const float4*)(sKc + q);
            cnt += (v.x > my) || (v.x == my && (q + 0) < t);
            cnt += (v.y > my) || (v.y == my && (q + 1) < t);
            cnt += (v.z > my) || (v.z == my && (q + 2) < t);
            cnt += (v.w > my) || (v.w == my && (q + 3) < t);
        }
        if (cnt < knext) {
            int o = sIDX[t];
            sNP[o] = cnt;
            sHS[o] = sH[o] * my;
            sIDXn[cnt] = o;
            atomicOr(&sSELn[o >> 5], 1u << (o & 31));
        }
    }
    __syncthreads();
    // twohop: P = intersect of complements over current neighbors, early exit
    bool act2 = (t < 500) && ((sSELn[t >> 5] >> (t & 31)) & 1u);
    if (act2) {
        uint4 P0 = *(const uint4*)(sSELn + 0);
        uint4 P1 = *(const uint4*)(sSELn + 4);
        uint4 P2 = *(const uint4*)(sSELn + 8);
        uint4 P3 = *(const uint4*)(sSELn + 12);
        bool anyP = true;
        for (int w = 0; w < 16 && anyP; ++w) {
            unsigned nb = sSEL[w] & ~sCP[t * MS + w];  // current neighbors
            while (nb) {
                int b = __ffs(nb) - 1;
                nb &= nb - 1;
                const uint4* cp = (const uint4*)(sCP + (w * 32 + b) * MS);
                uint4 c0 = cp[0], c1 = cp[1], c2 = cp[2], c3 = cp[3];
                P0.x &= c0.x; P0.y &= c0.y; P0.z &= c0.z; P0.w &= c0.w;
                P1.x &= c1.x; P1.y &= c1.y; P1.z &= c1.z; P1.w &= c1.w;
                P2.x &= c2.x; P2.y &= c2.y; P2.z &= c2.z; P2.w &= c2.w;
                P3.x &= c3.x; P3.y &= c3.y; P3.z &= c3.z; P3.w &= c3.w;
                unsigned o = P0.x | P0.y | P0.z | P0.w | P1.x | P1.y | P1.z | P1.w |
                             P2.x | P2.y | P2.z | P2.w | P3.x | P3.y | P3.z | P3.w;
                if (!o) { anyP = false; break; }
            }
        }
        int pc = __popc(P0.x) + __popc(P0.y) + __popc(P0.z) + __popc(P0.w) +
                 __popc(P1.x) + __popc(P1.y) + __popc(P1.z) + __popc(P1.w) +
                 __popc(P2.x) + __popc(P2.y) + __popc(P2.z) + __popc(P2.w) +
                 __popc(P3.x) + __popc(P3.y) + __popc(P3.z) + __popc(P3.w);
        uint4* cg = (uint4*)(CPg + t * MS);
        cg[0] = P0; cg[1] = P1; cg[2] = P2; cg[3] = P3;
        float rs = (float)(knext - pc);
        RSUMo[t] = rs;
        int np = sNP[t];
        SUo[t] = sHS[t] * Wdn[np] / rs;
        POSg[t] = np;
    }
    if (t < 16) SELM[t] = sSELn[t];
    if (t < knext) IDXL[t] = sIDXn[t];
}

extern "C" void kernel_launch(void* const* d_in, const int* in_sizes, int n_in,
                              void* d_out, int out_size, void* d_ws, size_t ws_size,
                              hipStream_t stream) {
    const float* g = (const float*)d_in[0];
    const float* h = (const float*)d_in[1];
    const float* W_top = (const float*)d_in[2];
    const float* b_top = (const float*)d_in[3];
    const float* Wp[4], *bp[4], *Wd[4], *bd[4];
    for (int i = 0; i < 4; ++i) {
        Wp[i] = (const float*)d_in[4 + 4 * i];
        bp[i] = (const float*)d_in[5 + 4 * i];
        Wd[i] = (const float*)d_in[6 + 4 * i];
        bd[i] = (const float*)d_in[7 + 4 * i];
    }
    float* out = (float*)d_out;

    unsigned* wsu = (unsigned*)d_ws;
    float* V = (float*)(wsu + 0);
    int* POSg = (int*)(wsu + 512);
    float* HSELo = (float*)(wsu + 1024);
    float* RSUMo = (float*)(wsu + 1536);
    float* SUo = (float*)(wsu + 2048);
    unsigned* SELM = wsu + 2560;   // 16 used, 32 reserved
    int* IDXL = (int*)(wsu + 2592);
    unsigned* CPg = wsu + 3104;    // 500*16
    unsigned* MA = wsu + 11104;    // 500*16

    k_dot<<<500, 1024, 0, stream>>>(h, W_top, g, V, MA);
    k_top<<<1, 1024, 0, stream>>>(MA, V, b_top, Wp[0], bp[0], out, POSg, IDXL,
                                  HSELo, SELM);
    k_twohop0<<<100, 256, 0, stream>>>(MA, IDXL, SELM, HSELo, Wd[0], CPg, RSUMo,
                                       SUo);
    k_layer<<<1, 1024, 0, stream>>>(CPg, SELM, POSg, IDXL, RSUMo, SUo, bd[0],
                                    Wp[1], bp[1], Wd[1], out, 400, 300, 500);
    k_layer<<<1, 1024, 0, stream>>>(CPg, SELM, POSg, IDXL, RSUMo, SUo, bd[1],
                                    Wp[2], bp[2], Wd[2], out, 300, 200, 900);
    k_layer<<<1, 1024, 0, stream>>>(CPg, SELM, POSg, IDXL, RSUMo, SUo, bd[2],
                                    Wp[3], bp[3], Wd[3], out, 200, 100, 1200);
    k_layer<<<1, 1024, 0, stream>>>(CPg, SELM, POSg, IDXL, RSUMo, SUo, bd[3],
                                    nullptr, nullptr, nullptr, out, 100, 0, 1400);
}

// Round 7
// 87.631 us; speedup vs baseline: 2.2681x; 1.3391x over previous
//
#include <hip/hip_runtime.h>

// All state in ORIGINAL 500-node index space + compact (rank-order) arrays.
// Complement representation: for layers >=1 the 2-hop pooled graph is ~99.5%
// dense, so we store each row's COMPLEMENT (~2-3 bits) in CP_A/CP_B.
// ws (u32 words): V@0, SHo@512, SC@1024, HSELo@1536, RSUMo@2048, SUc@2560,
// SUo@3072, SU2c@3584, SU2o@4096, SELA@4608(16), SELB@4624(16), IDXA@4640,
// IDXB@5152, CPA@5664(8000), CPB@13664(8000), MA@21664(8000)

#define MS 16

__device__ __forceinline__ float bitselF(unsigned m, int k, float v) {
    int s = ((int)(m << (31 - k))) >> 31;
    return __int_as_float(s & __float_as_int(v));
}
__device__ __forceinline__ float fbfly(float v) {
#pragma unroll
    for (int o = 32; o; o >>= 1) v += __shfl_xor(v, o);
    return v;
}
__device__ __forceinline__ int ibfly(int v) {
#pragma unroll
    for (int o = 32; o; o >>= 1) v += __shfl_xor(v, o);
    return v;
}

// V[row] = dot(h[row,:], Wt); MA[row] = bitmask of g row; zero SEL masks.
__global__ __launch_bounds__(1024) void k_dot(const float* __restrict__ h,
        const float* __restrict__ Wt, const float* __restrict__ g,
        float* __restrict__ V, unsigned* __restrict__ MA,
        unsigned* __restrict__ SEL2) {
    int row = blockIdx.x, t = threadIdx.x;
    if (row == 0 && t < 32) SEL2[t] = 0u;
    const float4* h4 = (const float4*)(h + (size_t)row * 32768);
    const float4* w4 = (const float4*)Wt;
    float acc = 0.f;
#pragma unroll
    for (int j = 0; j < 8; ++j) {
        float4 a = h4[t + 1024 * j], b = w4[t + 1024 * j];
        acc = fmaf(a.x, b.x, fmaf(a.y, b.y, fmaf(a.z, b.z, fmaf(a.w, b.w, acc))));
    }
    acc = fbfly(acc);
    __shared__ float red[16];
    if ((t & 63) == 0) red[t >> 6] = acc;
    __syncthreads();
    if (t == 0) {
        float s = 0.f;
        for (int i = 0; i < 16; ++i) s += red[i];
        V[row] = s;
    }
    if (t < 512) {
        float gv = (t < 500) ? g[row * 500 + t] : 0.f;
        unsigned long long bal = __ballot(gv != 0.f);
        if ((t & 63) == 0) {
            int w = t >> 6;
            MA[row * MS + 2 * w] = (unsigned)bal;
            MA[row * MS + 2 * w + 1] = (unsigned)(bal >> 32);
        }
    }
}

// Dense sparse-g matvec, wave per row (125 blocks).
// mode 0: y = relu(acc + c0), also out[r]. mode 1: y = sigmoid(relu(acc*c0+c1)).
__global__ __launch_bounds__(256) void k_row(const unsigned* __restrict__ MA,
        const float* __restrict__ x, const float* __restrict__ c0,
        const float* __restrict__ c1, float* __restrict__ y,
        float* __restrict__ out, int mode) {
    __shared__ float sv[512];
    int t = threadIdx.x;
    sv[t] = (t < 500) ? x[t] : 0.f;
    sv[t + 256] = (t + 256 < 500) ? x[t + 256] : 0.f;
    __syncthreads();
    int wid = t >> 6, lane = t & 63;
    int r = blockIdx.x * 4 + wid;
    float acc = 0.f;
#pragma unroll
    for (int j = 0; j < 8; ++j) {
        unsigned m = MA[r * MS + 2 * j + (lane >> 5)];
        acc += bitselF(m, lane & 31, sv[64 * j + lane]);
    }
    acc = fbfly(acc);
    if (lane == 0) {
        if (mode == 0) {
            float hv = fmaxf(acc + c0[0], 0.f);
            out[r] = hv;
            y[r] = hv;
        } else {
            float xx = fmaxf(acc * c0[0] + c1[0], 0.f);
            y[r] = 1.f / (1.f + expf(-xx));
        }
    }
}

// Stable top-knext rank of kk compact-ordered scores, wave per row.
// IDXc==nullptr -> compact index IS orig index (top level).
__global__ __launch_bounds__(256) void k_rank(const int* __restrict__ IDXc,
        const float* __restrict__ SCc, const float* __restrict__ SHo,
        unsigned* __restrict__ SELn, int* __restrict__ IDXn,
        float* __restrict__ HSELo, int kk, int knext) {
    int t = threadIdx.x, wid = t >> 6, lane = t & 63;
    int c = blockIdx.x * 4 + wid;
    float my = SCc[c];
    int cnt = 0;
    for (int j = lane; j < kk; j += 64) {
        float sj = SCc[j];
        cnt += (sj > my) || (sj == my && j < c);
    }
    cnt = ibfly(cnt);
    if (lane == 0 && cnt < knext) {
        int o = IDXc ? IDXc[c] : c;
        IDXn[cnt] = o;
        HSELo[o] = SHo[o] * my;
        atomicOr(&SELn[o >> 5], 1u << (o & 31));
    }
}

// Layer-0 twohop on sparse g (dense column scan), wave per selected row.
__global__ __launch_bounds__(256) void k_twohop0(const unsigned* __restrict__ MA,
        const int* __restrict__ IDXL, const unsigned* __restrict__ SELM,
        const float* __restrict__ HSELo, const float* __restrict__ Wd0,
        unsigned* __restrict__ CPg, float* __restrict__ RSUMo,
        float* __restrict__ SUc, float* __restrict__ SUo) {
    int wid = threadIdx.x >> 6, lane = threadIdx.x & 63;
    int r4 = blockIdx.x * 4 + wid;
    int i = IDXL[r4];
    __shared__ unsigned sSEL[16];
    __shared__ unsigned srow[4][16];
    __shared__ unsigned un2[4][16];
    if (threadIdx.x < 16) sSEL[threadIdx.x] = SELM[threadIdx.x];
    if (lane < 16) {
        srow[wid][lane] = MA[i * MS + lane];
        un2[wid][lane] = 0u;
    }
    __syncthreads();
    int part = lane >> 4, w = lane & 15;
    unsigned acc = 0;
    for (int k = part; k < 500; k += 4) {
        unsigned sel = (srow[wid][k >> 5] >> (k & 31)) & 1u;
        acc |= MA[k * MS + w] & (0u - sel);
    }
    atomicOr(&un2[wid][w], acc);
    __syncthreads();
    if (lane < 16) {
        unsigned Pw = sSEL[lane] & ~un2[wid][lane];
        CPg[i * MS + lane] = Pw;
        int pc = __popc(Pw);
        pc += __shfl_xor(pc, 1);
        pc += __shfl_xor(pc, 2);
        pc += __shfl_xor(pc, 4);
        pc += __shfl_xor(pc, 8);
        if (lane == 0) {
            float rs = (float)(400 - pc);
            RSUMo[i] = rs;
            float su = HSELo[i] * Wd0[r4] / rs;
            SUc[r4] = su;
            SUo[i] = su;
        }
    }
}

// Down-GCN (mode 0) or score-GCN (mode 1) via total - complement.
// Wave per compact row; redundant fixed-tree total per wave (deterministic).
__global__ __launch_bounds__(256) void k_mid(const int* __restrict__ IDXc,
        const unsigned* __restrict__ CP, const float* __restrict__ VALc,
        const float* __restrict__ VALo, const float* __restrict__ RSUMo,
        const float* __restrict__ c0, const float* __restrict__ c1,
        float* __restrict__ res_out, float* __restrict__ SHo,
        float* __restrict__ SU2c, float* __restrict__ SU2o,
        unsigned* __restrict__ SELn, int kk, int mode) {
    int t = threadIdx.x, wid = t >> 6, lane = t & 63;
    int c = blockIdx.x * 4 + wid;
    if (mode == 1 && blockIdx.x == 0 && t < 16) SELn[t] = 0u;
    float a = 0.f;
    int j4 = lane * 4;
    if (j4 < kk) {
        float4 v = *(const float4*)(VALc + j4);
        a += (v.x + v.y) + (v.z + v.w);
    }
    j4 += 256;
    if (j4 < kk) {
        float4 v = *(const float4*)(VALc + j4);
        a += (v.x + v.y) + (v.z + v.w);
    }
    float tot = fbfly(a);
    int i = IDXc[c];
    float corr = 0.f;
    if (lane < 16) {
        unsigned m = CP[i * MS + lane];
        while (m) {
            int b = __ffs(m) - 1;
            m &= m - 1;
            corr += VALo[lane * 32 + b];
        }
    }
    corr = fbfly(corr);
    if (lane == 0) {
        if (mode == 0) {
            float hv = fmaxf(tot - corr + c0[0], 0.f);
            res_out[c] = hv;
            SHo[i] = hv;
            float s2 = hv / RSUMo[i];
            SU2c[c] = s2;
            SU2o[i] = s2;
        } else {
            float x = fmaxf((tot - corr) * c0[0] + c1[0], 0.f);
            res_out[c] = 1.f / (1.f + expf(-x));
        }
    }
}

// 2-hop for layers >=1: newCP[i] = SELn & intersect of CP[j] over current
// neighbors j of i; early exit when empty (~2-4 iters, graphs ~99.5% dense).
__global__ __launch_bounds__(256) void k_hop(const unsigned* __restrict__ SELcur,
        const unsigned* __restrict__ CPcur, const unsigned* __restrict__ SELn,
        const int* __restrict__ IDXn, const float* __restrict__ HSELo,
        const float* __restrict__ Wdn, unsigned* __restrict__ CPn,
        float* __restrict__ RSUMo, float* __restrict__ SUc,
        float* __restrict__ SUo, int knext) {
    int t = threadIdx.x, wid = t >> 6, lane = t & 63;
    int c = blockIdx.x * 4 + wid;
    int i = IDXn[c];
    unsigned P = (lane < 16) ? SELn[lane] : 0u;
    bool alive = true;
    for (int w = 0; w < 16 && alive; ++w) {
        unsigned nb = SELcur[w] & ~CPcur[i * MS + w];
        while (nb) {
            int b = __ffs(nb) - 1;
            nb &= nb - 1;
            int j = w * 32 + b;
            if (lane < 16) P &= CPcur[j * MS + lane];
            if (__ballot(P != 0) == 0ull) { alive = false; break; }
        }
    }
    int pc = ibfly(__popc(P));
    if (lane < 16) CPn[i * MS + lane] = P;
    if (lane == 0) {
        float rs = (float)(knext - pc);
        RSUMo[i] = rs;
        float su = HSELo[i] * Wdn[c] / rs;
        SUc[c] = su;
        SUo[i] = su;
    }
}

extern "C" void kernel_launch(void* const* d_in, const int* in_sizes, int n_in,
                              void* d_out, int out_size, void* d_ws, size_t ws_size,
                              hipStream_t stream) {
    const float* g = (const float*)d_in[0];
    const float* h = (const float*)d_in[1];
    const float* W_top = (const float*)d_in[2];
    const float* b_top = (const float*)d_in[3];
    const float* Wp[4], *bp[4], *Wd[4], *bd[4];
    for (int i = 0; i < 4; ++i) {
        Wp[i] = (const float*)d_in[4 + 4 * i];
        bp[i] = (const float*)d_in[5 + 4 * i];
        Wd[i] = (const float*)d_in[6 + 4 * i];
        bd[i] = (const float*)d_in[7 + 4 * i];
    }
    float* out = (float*)d_out;

    unsigned* wsu = (unsigned*)d_ws;
    float* V = (float*)(wsu + 0);
    float* SHo = (float*)(wsu + 512);
    float* SC = (float*)(wsu + 1024);
    float* HSELo = (float*)(wsu + 1536);
    float* RSUMo = (float*)(wsu + 2048);
    float* SUc = (float*)(wsu + 2560);
    float* SUo = (float*)(wsu + 3072);
    float* SU2c = (float*)(wsu + 3584);
    float* SU2o = (float*)(wsu + 4096);
    unsigned* SELA = wsu + 4608;
    unsigned* SELB = wsu + 4624;
    int* IDXA = (int*)(wsu + 4640);
    int* IDXB = (int*)(wsu + 5152);
    unsigned* CPA = wsu + 5664;
    unsigned* CPB = wsu + 13664;
    unsigned* MA = wsu + 21664;

    k_dot<<<500, 1024, 0, stream>>>(h, W_top, g, V, MA, SELA);
    k_row<<<125, 256, 0, stream>>>(MA, V, b_top, nullptr, SHo, out, 0);
    k_row<<<125, 256, 0, stream>>>(MA, SHo, Wp[0], bp[0], SC, nullptr, 1);
    k_rank<<<125, 256, 0, stream>>>(nullptr, SC, SHo, SELA, IDXA, HSELo, 500, 400);
    k_twohop0<<<100, 256, 0, stream>>>(MA, IDXA, SELA, HSELo, Wd[0], CPA, RSUMo,
                                       SUc, SUo);
    // layer 0: kk=400 -> knext=300 (cur A, next B)
    k_mid<<<100, 256, 0, stream>>>(IDXA, CPA, SUc, SUo, RSUMo, bd[0], nullptr,
                                   out + 500, SHo, SU2c, SU2o, nullptr, 400, 0);
    k_mid<<<100, 256, 0, stream>>>(IDXA, CPA, SU2c, SU2o, RSUMo, Wp[1], bp[1],
                                   SC, nullptr, nullptr, nullptr, SELB, 400, 1);
    k_rank<<<100, 256, 0, stream>>>(IDXA, SC, SHo, SELB, IDXB, HSELo, 400, 300);
    k_hop<<<75, 256, 0, stream>>>(SELA, CPA, SELB, IDXB, HSELo, Wd[1], CPB,
                                  RSUMo, SUc, SUo, 300);
    // layer 1: kk=300 -> knext=200 (cur B, next A)
    k_mid<<<75, 256, 0, stream>>>(IDXB, CPB, SUc, SUo, RSUMo, bd[1], nullptr,
                                  out + 900, SHo, SU2c, SU2o, nullptr, 300, 0);
    k_mid<<<75, 256, 0, stream>>>(IDXB, CPB, SU2c, SU2o, RSUMo, Wp[2], bp[2],
                                  SC, nullptr, nullptr, nullptr, SELA, 300, 1);
    k_rank<<<75, 256, 0, stream>>>(IDXB, SC, SHo, SELA, IDXA, HSELo, 300, 200);
    k_hop<<<50, 256, 0, stream>>>(SELB, CPB, SELA, IDXA, HSELo, Wd[2], CPA,
                                  RSUMo, SUc, SUo, 200);
    // layer 2: kk=200 -> knext=100 (cur A, next B)
    k_mid<<<50, 256, 0, stream>>>(IDXA, CPA, SUc, SUo, RSUMo, bd[2], nullptr,
                                  out + 1200, SHo, SU2c, SU2o, nullptr, 200, 0);
    k_mid<<<50, 256, 0, stream>>>(IDXA, CPA, SU2c, SU2o, RSUMo, Wp[3], bp[3],
                                  SC, nullptr, nullptr, nullptr, SELB, 200, 1);
    k_rank<<<50, 256, 0, stream>>>(IDXA, SC, SHo, SELB, IDXB, HSELo, 200, 100);
    k_hop<<<25, 256, 0, stream>>>(SELA, CPA, SELB, IDXB, HSELo, Wd[3], CPB,
                                  RSUMo, SUc, SUo, 100);
    // layer 3: kk=100, output only
    k_mid<<<25, 256, 0, stream>>>(IDXB, CPB, SUc, SUo, RSUMo, bd[3], nullptr,
                                  out + 1400, SHo, SU2c, SU2o, nullptr, 100, 0);
}